// Round 8
// baseline (51557.123 us; speedup 1.0000x reference)
//
#include <hip/hip_runtime.h>
#include <hip/hip_fp16.h>
#include <math.h>

#define Hn 1024
#define Bn 4096
#define INW 33
#define OUTS (Bn * Hn)
#define ROWP 1024   // packets per exchange row: [h0 half (512) | h1 half (512)]

typedef _Float16 half2v __attribute__((ext_vector_type(2)));
typedef unsigned uint4v __attribute__((ext_vector_type(4)));

__device__ __forceinline__ float sigmoidf_(float x) {
    return 1.0f / (1.0f + __expf(-x));
}
__device__ __forceinline__ float tanhf_(float x) {
    float e = __expf(-2.0f * fabsf(x));
    float r = (1.0f - e) / (1.0f + e);
    return copysignf(r, x);
}
__device__ __forceinline__ unsigned pack2(float a, float b) {
    __half2 h = __floats2half2_rn(a, b);
    return __builtin_bit_cast(unsigned, h);
}
__device__ __forceinline__ float dot2acc(unsigned w, unsigned hv, float acc) {
#if __has_builtin(__builtin_amdgcn_fdot2)
    return __builtin_amdgcn_fdot2(__builtin_bit_cast(half2v, w),
                                  __builtin_bit_cast(half2v, hv), acc, false);
#else
    __half2 wh = __builtin_bit_cast(__half2, w);
    __half2 hh = __builtin_bit_cast(__half2, hv);
    float2 wf = __half22float2(wh), hf = __half22float2(hh);
    return acc + wf.x * hf.x + wf.y * hf.y;
#endif
}

// Slice spin: lane i polls packet slice[i] (64 packets = 512 B = 4 lines per
// wave per round, one 8 B load per lane). Detection and data capture are the
// SAME load — when the whole slice is tagged, the data is already in
// registers. Hard spin, no sleep (sleep was bistable in R5/R6).
__device__ __forceinline__ unsigned spin_slice(const unsigned long long* slice,
                                               int lane, unsigned tag) {
    unsigned long long v;
    int rounds = 0;
    for (;;) {
        asm volatile("global_load_dwordx2 %0, %1, off sc0 sc1\n\t"
                     "s_waitcnt vmcnt(0)"
                     : "=v"(v) : "v"(slice + lane) : "memory");
        if (__all((unsigned)(v >> 32) == tag)) break;
        if (++rounds > (1 << 24)) break;   // bailout: wrong answer beats a wedged GPU
    }
    return (unsigned)v;
}

__device__ __forceinline__ void store16_coherent(void* dst, uint4v v) {
    asm volatile("global_store_dwordx4 %0, %1, off sc0 sc1"
                 :: "v"(dst), "v"(v) : "memory");
}

// xin = [x | ip_emb[ip] | port_emb[port]]  (4096 x 33)
__global__ void prep_kernel(const float* __restrict__ x, const int* __restrict__ ip,
                            const int* __restrict__ port, const float* __restrict__ ip_emb,
                            const float* __restrict__ port_emb, float* __restrict__ xin) {
    int gid = blockIdx.x * blockDim.x + threadIdx.x;
    if (gid < Bn * INW) {
        int t = gid / INW;
        int k = gid - t * INW;
        float v;
        if (k < 17) {
            v = x[t * 17 + k];
        } else if (k < 25) {
            v = ip_emb[ip[t * 8 + (k - 17)]];
        } else {
            int kk = k - 25;
            v = port_emb[port[t * 2 + (kk >> 2)] * 4 + (kk & 3)];
        }
        xin[gid] = v;
    }
}

// Skewed supersteps (R7 protocol): row s holds [h0[s] | h1[s-1]], all packets
// tagged s+1. Superstep s: L0 computes step s from row s-1's h0 half; L1
// computes step s-1 from BOTH halves of row s-1 (one tag phase).
// 48 fat blocks (16 L0 + 32 L1, 1024 threads each): fewer sync participants
// (max-of-N jitter), per-wave slice spins, 2 barriers, double-buffered LDS.
__global__ void __launch_bounds__(1024, 2) lstm_kernel(
    const float* __restrict__ xin,
    const float* __restrict__ hid0, const float* __restrict__ cel0,
    const float* __restrict__ Wih0, const float* __restrict__ Whh0,
    const float* __restrict__ bih0, const float* __restrict__ bhh0,
    const float* __restrict__ Wih1, const float* __restrict__ Whh1,
    const float* __restrict__ bih1, const float* __restrict__ bhh1,
    float* __restrict__ out,
    unsigned long long* __restrict__ rowpkt)  // [Bn+1][ROWP]
{
    __shared__ unsigned hs2[2][1024];          // double-buffered half2 h chunks
    __shared__ unsigned long long stg[32];     // outgoing packet staging
    const int tid  = threadIdx.x;
    const int lane = tid & 63;
    const int wave = tid >> 6;                 // 0..15
    const int bx   = blockIdx.x;

    if (bx < 16) {
        // ========== layer 0 : 16 blocks x 1024 thr, wave owns 4 h-indices ====
        const int j0 = bx * 64 + wave * 4;
        unsigned w2[4][4][8];     // f16-pair weights of Whh0
        float    wx[4][4];        // fp32 x-weights (lane < 33)
        float    bs[4][4];
#pragma unroll
        for (int jj = 0; jj < 4; ++jj) {
#pragma unroll
            for (int g = 0; g < 4; ++g) {
                const int row = g * Hn + (j0 + jj);
                const float* wr = Whh0 + (size_t)row * Hn;
#pragma unroll
                for (int k = 0; k < 8; ++k) {
                    int c = lane + 64 * k;
                    w2[jj][g][k] = pack2(wr[2 * c], wr[2 * c + 1]);
                }
                wx[jj][g] = (lane < INW) ? Wih0[row * INW + lane] : 0.0f;
                bs[jj][g] = bih0[row] + bhh0[row];
            }
        }
        float cst[4], hcur[4];
#pragma unroll
        for (int jj = 0; jj < 4; ++jj) { cst[jj] = cel0[j0 + jj]; hcur[jj] = 0.0f; }

        for (int s = 0; s < Bn; ++s) {
            const int b = s & 1;
            float xv = xin[s * INW + (lane < INW ? lane : 0)];  // prefetch (L2-hot)
            if (wave < 8) {                    // h0 half = 512 packets = 8 slices
                if (s == 0) {
                    int q = wave * 64 + lane;
                    hs2[0][q] = pack2(hid0[2 * q], hid0[2 * q + 1]);
                } else {
                    unsigned d = spin_slice(rowpkt + (size_t)(s - 1) * ROWP + wave * 64,
                                            lane, (unsigned)s);
                    hs2[b][wave * 64 + lane] = d;
                }
            }
            __syncthreads();                   // barrier A: hs2[b] ready

            float acc[4][4];
#pragma unroll
            for (int jj = 0; jj < 4; ++jj)
#pragma unroll
                for (int g = 0; g < 4; ++g) acc[jj][g] = wx[jj][g] * xv;
#pragma unroll
            for (int k = 0; k < 8; ++k) {
                unsigned hv = hs2[b][lane + 64 * k];   // 2-way bank alias: free
#pragma unroll
                for (int jj = 0; jj < 4; ++jj)
#pragma unroll
                    for (int g = 0; g < 4; ++g)
                        acc[jj][g] = dot2acc(w2[jj][g][k], hv, acc[jj][g]);
            }

#pragma unroll
            for (int off = 32; off >= 1; off >>= 1)
#pragma unroll
                for (int jj = 0; jj < 4; ++jj)
#pragma unroll
                    for (int g = 0; g < 4; ++g)
                        acc[jj][g] += __shfl_xor(acc[jj][g], off);

#pragma unroll
            for (int jj = 0; jj < 4; ++jj) {
                float gi = sigmoidf_(acc[jj][0] + bs[jj][0]);
                float gf = sigmoidf_(acc[jj][1] + bs[jj][1]);
                float gg = tanhf_   (acc[jj][2] + bs[jj][2]);
                float go = sigmoidf_(acc[jj][3] + bs[jj][3]);
                cst[jj] = gf * cst[jj] + gi * gg;
                hcur[jj] = go * tanhf_(cst[jj]);
            }
            // stage 2 packets per wave; wave 0 bursts the block's 256 B segment
            if (lane == 0) {
                unsigned long long tw = ((unsigned long long)(s + 1)) << 32;
                stg[2 * wave]     = tw | pack2(hcur[0], hcur[1]);
                stg[2 * wave + 1] = tw | pack2(hcur[2], hcur[3]);
            }
            __syncthreads();                   // barrier C: stg ready + hs2 reads done
            if (wave == 0 && lane < 16) {
                uint4v v = *(const uint4v*)&stg[2 * lane];
                char* dst = (char*)(rowpkt + (size_t)s * ROWP) + bx * 256 + lane * 16;
                store16_coherent(dst, v);
            }
        }
        if (lane == 0) {
#pragma unroll
            for (int jj = 0; jj < 4; ++jj) {
                out[OUTS + j0 + jj] = hcur[jj];            // hf layer 0
                out[OUTS + 2 * Hn + j0 + jj] = cst[jj];    // cf layer 0
            }
        }
    } else {
        // ========== layer 1 : 32 blocks x 1024 thr, wave owns 2 h-indices ====
        const int blk = bx - 16;
        const int j0  = blk * 32 + wave * 2;
        unsigned w2[2][4][16];    // k<8: Wih1 (vs h0[t]) ; k>=8: Whh1 (vs h1[t-1])
        float    bs[2][4];
#pragma unroll
        for (int jj = 0; jj < 2; ++jj) {
#pragma unroll
            for (int g = 0; g < 4; ++g) {
                const int row = g * Hn + (j0 + jj);
                const float* wr1 = Wih1 + (size_t)row * Hn;
                const float* wr2 = Whh1 + (size_t)row * Hn;
#pragma unroll
                for (int k = 0; k < 8; ++k) {
                    int c = lane + 64 * k;
                    w2[jj][g][k]     = pack2(wr1[2 * c], wr1[2 * c + 1]);
                    w2[jj][g][8 + k] = pack2(wr2[2 * c], wr2[2 * c + 1]);
                }
                bs[jj][g] = bih1[row] + bhh1[row];
            }
        }
        float cst[2], hcur[2];
#pragma unroll
        for (int jj = 0; jj < 2; ++jj) { cst[jj] = cel0[Hn + j0 + jj]; hcur[jj] = 0.0f; }

        // publish initial h1 into row 0's h1 half (tag 1)
        if (wave == 0 && lane < 8) {
            int base = Hn + blk * 32 + 4 * lane;
            uint4v v;
            v.x = pack2(hid0[base],     hid0[base + 1]);  v.y = 1u;
            v.z = pack2(hid0[base + 2], hid0[base + 3]);  v.w = 1u;
            char* dst = (char*)(rowpkt + 512) + blk * 128 + lane * 16;
            store16_coherent(dst, v);
        }

        for (int s = 1; s <= Bn; ++s) {
            const int t = s - 1;               // LSTM step this superstep computes
            const int b = s & 1;
            // 16 waves cover the full 1024-packet row (h0 | h1)
            unsigned d = spin_slice(rowpkt + (size_t)(s - 1) * ROWP + wave * 64,
                                    lane, (unsigned)s);
            hs2[b][wave * 64 + lane] = d;
            __syncthreads();                   // barrier A

            float acc[2][4];
#pragma unroll
            for (int jj = 0; jj < 2; ++jj)
#pragma unroll
                for (int g = 0; g < 4; ++g) acc[jj][g] = 0.0f;
#pragma unroll
            for (int k = 0; k < 16; ++k) {
                unsigned hv = hs2[b][lane + 64 * k];
#pragma unroll
                for (int jj = 0; jj < 2; ++jj)
#pragma unroll
                    for (int g = 0; g < 4; ++g)
                        acc[jj][g] = dot2acc(w2[jj][g][k], hv, acc[jj][g]);
            }

#pragma unroll
            for (int off = 32; off >= 1; off >>= 1)
#pragma unroll
                for (int jj = 0; jj < 2; ++jj)
#pragma unroll
                    for (int g = 0; g < 4; ++g)
                        acc[jj][g] += __shfl_xor(acc[jj][g], off);

#pragma unroll
            for (int jj = 0; jj < 2; ++jj) {
                float gi = sigmoidf_(acc[jj][0] + bs[jj][0]);
                float gf = sigmoidf_(acc[jj][1] + bs[jj][1]);
                float gg = tanhf_   (acc[jj][2] + bs[jj][2]);
                float go = sigmoidf_(acc[jj][3] + bs[jj][3]);
                cst[jj] = gf * cst[jj] + gi * gg;
                hcur[jj] = go * tanhf_(cst[jj]);
            }
            if (lane == 0) {
                unsigned long long tw = ((unsigned long long)(s + 1)) << 32;
                stg[wave] = tw | pack2(hcur[0], hcur[1]);
                float2 o2 = make_float2(fmaxf(hcur[0], 0.0f), fmaxf(hcur[1], 0.0f));
                *(float2*)(out + (size_t)t * Hn + j0) = o2;   // outputs[t] = relu(h1)
            }
            __syncthreads();                   // barrier C: stg ready + hs2 reads done
            if (wave == 0 && lane < 8) {
                uint4v v = *(const uint4v*)&stg[2 * lane];
                char* dst = (char*)(rowpkt + (size_t)s * ROWP + 512) + blk * 128 + lane * 16;
                store16_coherent(dst, v);      // h1[t] into row s's h1 half
            }
        }
        if (lane == 0) {
#pragma unroll
            for (int jj = 0; jj < 2; ++jj) {
                out[OUTS + Hn + j0 + jj] = hcur[jj];           // hf layer 1
                out[OUTS + 3 * Hn + j0 + jj] = cst[jj];        // cf layer 1
            }
        }
    }
}

extern "C" void kernel_launch(void* const* d_in, const int* in_sizes, int n_in,
                              void* d_out, int out_size, void* d_ws, size_t ws_size,
                              hipStream_t stream) {
    const float* x        = (const float*)d_in[0];
    const int*   ip       = (const int*)d_in[1];
    const int*   port     = (const int*)d_in[2];
    const float* hidden   = (const float*)d_in[3];
    const float* cell     = (const float*)d_in[4];
    const float* ip_emb   = (const float*)d_in[5];
    const float* port_emb = (const float*)d_in[6];
    const float* Wih0     = (const float*)d_in[7];
    const float* Whh0     = (const float*)d_in[8];
    const float* bih0     = (const float*)d_in[9];
    const float* bhh0     = (const float*)d_in[10];
    const float* Wih1     = (const float*)d_in[11];
    const float* Whh1     = (const float*)d_in[12];
    const float* bih1     = (const float*)d_in[13];
    const float* bhh1     = (const float*)d_in[14];
    float* out = (float*)d_out;

    // ws layout: rowpkt ((Bn+1) x 1024 u64 = 33.6 MB) | xin (4096x33 f32).
    // Tags are s+1 in the high 32 bits; 0xAA poison never matches -> no
    // zeroing pass needed.
    unsigned long long* rowpkt = (unsigned long long*)d_ws;
    float* xin = (float*)(rowpkt + (size_t)(Bn + 1) * ROWP);

    prep_kernel<<<dim3((Bn * INW + 255) / 256), dim3(256), 0, stream>>>(
        x, ip, port, ip_emb, port_emb, xin);

    lstm_kernel<<<dim3(48), dim3(1024), 0, stream>>>(
        xin, hidden, cell, Wih0, Whh0, bih0, bhh0, Wih1, Whh1, bih1, bhh1,
        out, rowpkt);
}

// Round 9
// 16983.736 us; speedup vs baseline: 3.0357x; 3.0357x over previous
//
#include <hip/hip_runtime.h>
#include <hip/hip_fp16.h>
#include <math.h>

#define Hn 1024
#define Bn 4096
#define INW 33
#define OUTS (Bn * Hn)
#define TPB 512
#define ROWP 1024   // packets per exchange row: [h0 half (512) | h1 half (512)]

typedef _Float16 half2v __attribute__((ext_vector_type(2)));
typedef unsigned uint4v __attribute__((ext_vector_type(4)));

__device__ __forceinline__ float sigmoidf_(float x) {
    return 1.0f / (1.0f + __expf(-x));
}
__device__ __forceinline__ float tanhf_(float x) {
    float e = __expf(-2.0f * fabsf(x));
    float r = (1.0f - e) / (1.0f + e);
    return copysignf(r, x);
}
__device__ __forceinline__ unsigned pack2(float a, float b) {
    __half2 h = __floats2half2_rn(a, b);
    return __builtin_bit_cast(unsigned, h);
}
__device__ __forceinline__ float dot2acc(unsigned w, unsigned hv, float acc) {
#if __has_builtin(__builtin_amdgcn_fdot2)
    return __builtin_amdgcn_fdot2(__builtin_bit_cast(half2v, w),
                                  __builtin_bit_cast(half2v, hv), acc, false);
#else
    __half2 wh = __builtin_bit_cast(__half2, w);
    __half2 hh = __builtin_bit_cast(__half2, hv);
    float2 wf = __half22float2(wh), hf = __half22float2(hh);
    return acc + wf.x * hf.x + wf.y * hf.y;
#endif
}

// Slice spin: lane i polls packet slice[i] (64 packets = 4 lines per wave
// per round). Detection and data capture are the SAME load — once the whole
// slice carries the tag, the half2 payloads are already in registers.
// Hard spin (sleep was bistable); R3 showed read-request volume is not a
// limiter at this scale.
__device__ __forceinline__ unsigned spin_slice(const unsigned long long* slice,
                                               int lane, unsigned tag) {
    unsigned long long v;
    int rounds = 0;
    for (;;) {
        asm volatile("global_load_dwordx2 %0, %1, off sc0 sc1\n\t"
                     "s_waitcnt vmcnt(0)"
                     : "=v"(v) : "v"(slice + lane) : "memory");
        if (__all((unsigned)(v >> 32) == tag)) break;
        if (++rounds > (1 << 24)) break;   // bailout: wrong answer beats a wedged GPU
    }
    return (unsigned)v;
}

// Dual-slice spin (L1): both loads in flight, one waitcnt -> same round
// latency as a single-slice spin.
__device__ __forceinline__ void spin_slice2(const unsigned long long* sliceA,
                                            const unsigned long long* sliceB,
                                            int lane, unsigned tag,
                                            unsigned& dA, unsigned& dB) {
    unsigned long long va, vb;
    int rounds = 0;
    for (;;) {
        asm volatile("global_load_dwordx2 %0, %2, off sc0 sc1\n\t"
                     "global_load_dwordx2 %1, %3, off sc0 sc1\n\t"
                     "s_waitcnt vmcnt(0)"
                     : "=v"(va), "=v"(vb)
                     : "v"(sliceA + lane), "v"(sliceB + lane) : "memory");
        bool ok = ((unsigned)(va >> 32) == tag) & ((unsigned)(vb >> 32) == tag);
        if (__all(ok)) break;
        if (++rounds > (1 << 24)) break;   // bailout
    }
    dA = (unsigned)va;
    dB = (unsigned)vb;
}

__device__ __forceinline__ void store16_coherent(void* dst, uint4v v) {
    asm volatile("global_store_dwordx4 %0, %1, off sc0 sc1"
                 :: "v"(dst), "v"(v) : "memory");
}

// xin = [x | ip_emb[ip] | port_emb[port]]  (4096 x 33)
__global__ void prep_kernel(const float* __restrict__ x, const int* __restrict__ ip,
                            const int* __restrict__ port, const float* __restrict__ ip_emb,
                            const float* __restrict__ port_emb, float* __restrict__ xin) {
    int gid = blockIdx.x * blockDim.x + threadIdx.x;
    if (gid < Bn * INW) {
        int t = gid / INW;
        int k = gid - t * INW;
        float v;
        if (k < 17) {
            v = x[t * 17 + k];
        } else if (k < 25) {
            v = ip_emb[ip[t * 8 + (k - 17)]];
        } else {
            int kk = k - 25;
            v = port_emb[port[t * 2 + (kk >> 2)] * 4 + (kk & 3)];
        }
        xin[gid] = v;
    }
}

// Skewed supersteps (R7 protocol): row s holds [h0[s] | h1[s-1]], all packets
// tagged s+1. Superstep s: L0 computes step s from row s-1's h0 half; L1
// computes step s-1 from BOTH halves of row s-1 (single tag phase).
// R9: slice-spin (detect==data, no serialized 4 KB row read), 2 barriers,
// double-buffered LDS. 512-thr blocks, VGPR 128 (R8 lesson: 1024-thr blocks
// cap VGPR at 64 -> weight spill catastrophe).
__global__ void __launch_bounds__(TPB, 2) lstm_kernel(
    const float* __restrict__ xin,
    const float* __restrict__ hid0, const float* __restrict__ cel0,
    const float* __restrict__ Wih0, const float* __restrict__ Whh0,
    const float* __restrict__ bih0, const float* __restrict__ bhh0,
    const float* __restrict__ Wih1, const float* __restrict__ Whh1,
    const float* __restrict__ bih1, const float* __restrict__ bhh1,
    float* __restrict__ out,
    unsigned long long* __restrict__ rowpkt)  // [Bn+1][ROWP]
{
    __shared__ unsigned hs2[2][1024];          // double-buffered half2 h chunks
    __shared__ unsigned long long stg[16];     // outgoing packet staging
    const int tid  = threadIdx.x;
    const int lane = tid & 63;
    const int wave = tid >> 6;                 // 0..7
    const int bx   = blockIdx.x;

    if (bx < 32) {
        // ========== layer 0 : 32 blocks, wave owns 4 h-indices ==========
        const int j0 = bx * 32 + wave * 4;
        unsigned w2[4][4][8];     // f16-pair weights of Whh0
        float    wx[4][4];        // fp32 x-weights (lane < 33)
        float    bs[4][4];
#pragma unroll
        for (int jj = 0; jj < 4; ++jj) {
#pragma unroll
            for (int g = 0; g < 4; ++g) {
                const int row = g * Hn + (j0 + jj);
                const float* wr = Whh0 + (size_t)row * Hn;
#pragma unroll
                for (int k = 0; k < 8; ++k) {
                    int c = lane + 64 * k;
                    w2[jj][g][k] = pack2(wr[2 * c], wr[2 * c + 1]);
                }
                wx[jj][g] = (lane < INW) ? Wih0[row * INW + lane] : 0.0f;
                bs[jj][g] = bih0[row] + bhh0[row];
            }
        }
        float cst[4], hcur[4];
#pragma unroll
        for (int jj = 0; jj < 4; ++jj) { cst[jj] = cel0[j0 + jj]; hcur[jj] = 0.0f; }

        for (int s = 0; s < Bn; ++s) {
            const int b = s & 1;
            float xv = xin[s * INW + (lane < INW ? lane : 0)];  // prefetch (L2-hot)
            // waves 0-7 each spin one 64-packet slice of the h0 half
            if (s == 0) {
                int q = wave * 64 + lane;
                hs2[0][q] = pack2(hid0[2 * q], hid0[2 * q + 1]);
            } else {
                unsigned d = spin_slice(rowpkt + (size_t)(s - 1) * ROWP + wave * 64,
                                        lane, (unsigned)s);
                hs2[b][wave * 64 + lane] = d;
            }
            __syncthreads();                   // barrier A: hs2[b] ready

            float acc[4][4];
#pragma unroll
            for (int jj = 0; jj < 4; ++jj)
#pragma unroll
                for (int g = 0; g < 4; ++g) acc[jj][g] = wx[jj][g] * xv;
#pragma unroll
            for (int k = 0; k < 8; ++k) {
                unsigned hv = hs2[b][lane + 64 * k];   // 2-way bank alias: free
#pragma unroll
                for (int jj = 0; jj < 4; ++jj)
#pragma unroll
                    for (int g = 0; g < 4; ++g)
                        acc[jj][g] = dot2acc(w2[jj][g][k], hv, acc[jj][g]);
            }

#pragma unroll
            for (int off = 32; off >= 1; off >>= 1)
#pragma unroll
                for (int jj = 0; jj < 4; ++jj)
#pragma unroll
                    for (int g = 0; g < 4; ++g)
                        acc[jj][g] += __shfl_xor(acc[jj][g], off);

#pragma unroll
            for (int jj = 0; jj < 4; ++jj) {
                float gi = sigmoidf_(acc[jj][0] + bs[jj][0]);
                float gf = sigmoidf_(acc[jj][1] + bs[jj][1]);
                float gg = tanhf_   (acc[jj][2] + bs[jj][2]);
                float go = sigmoidf_(acc[jj][3] + bs[jj][3]);
                cst[jj] = gf * cst[jj] + gi * gg;
                hcur[jj] = go * tanhf_(cst[jj]);
            }
            // stage 2 packets per wave; wave 0 bursts the block's 128 B segment
            if (lane == 0) {
                unsigned long long tw = ((unsigned long long)(s + 1)) << 32;
                stg[2 * wave]     = tw | pack2(hcur[0], hcur[1]);
                stg[2 * wave + 1] = tw | pack2(hcur[2], hcur[3]);
            }
            __syncthreads();                   // barrier B: stg ready; hs2 reads done
            if (wave == 0 && lane < 8) {
                uint4v v = *(const uint4v*)&stg[2 * lane];
                char* dst = (char*)(rowpkt + (size_t)s * ROWP) + bx * 128 + lane * 16;
                store16_coherent(dst, v);
            }
        }
        if (lane == 0) {
#pragma unroll
            for (int jj = 0; jj < 4; ++jj) {
                out[OUTS + j0 + jj] = hcur[jj];            // hf layer 0
                out[OUTS + 2 * Hn + j0 + jj] = cst[jj];    // cf layer 0
            }
        }
    } else {
        // ========== layer 1 : 64 blocks, wave owns 2 h-indices ==========
        const int blk = bx - 32;
        const int j0  = blk * 16 + wave * 2;
        unsigned w2[2][4][16];    // k<8: Wih1 (vs h0[t]) ; k>=8: Whh1 (vs h1[t-1])
        float    bs[2][4];
#pragma unroll
        for (int jj = 0; jj < 2; ++jj) {
#pragma unroll
            for (int g = 0; g < 4; ++g) {
                const int row = g * Hn + (j0 + jj);
                const float* wr1 = Wih1 + (size_t)row * Hn;
                const float* wr2 = Whh1 + (size_t)row * Hn;
#pragma unroll
                for (int k = 0; k < 8; ++k) {
                    int c = lane + 64 * k;
                    w2[jj][g][k]     = pack2(wr1[2 * c], wr1[2 * c + 1]);
                    w2[jj][g][8 + k] = pack2(wr2[2 * c], wr2[2 * c + 1]);
                }
                bs[jj][g] = bih1[row] + bhh1[row];
            }
        }
        float cst[2], hcur[2];
#pragma unroll
        for (int jj = 0; jj < 2; ++jj) { cst[jj] = cel0[Hn + j0 + jj]; hcur[jj] = 0.0f; }

        // publish initial h1 into row 0's h1 half (tag 1)
        if (wave == 0 && lane < 4) {
            int base = Hn + blk * 16 + 4 * lane;
            uint4v v;
            v.x = pack2(hid0[base],     hid0[base + 1]);  v.y = 1u;
            v.z = pack2(hid0[base + 2], hid0[base + 3]);  v.w = 1u;
            char* dst = (char*)(rowpkt + 512) + blk * 64 + lane * 16;
            store16_coherent(dst, v);
        }

        for (int s = 1; s <= Bn; ++s) {
            const int t = s - 1;               // LSTM step this superstep computes
            const int b = s & 1;
            // 8 waves x 2 slices cover the full 1024-packet row (h0 | h1)
            const unsigned long long* rb = rowpkt + (size_t)(s - 1) * ROWP;
            unsigned dA, dB;
            spin_slice2(rb + wave * 64, rb + 512 + wave * 64, lane, (unsigned)s, dA, dB);
            hs2[b][wave * 64 + lane]       = dA;   // h0[t] chunk
            hs2[b][512 + wave * 64 + lane] = dB;   // h1[t-1] chunk
            __syncthreads();                   // barrier A: hs2[b] ready

            float acc[2][4];
#pragma unroll
            for (int jj = 0; jj < 2; ++jj)
#pragma unroll
                for (int g = 0; g < 4; ++g) acc[jj][g] = 0.0f;
#pragma unroll
            for (int k = 0; k < 16; ++k) {
                unsigned hv = hs2[b][lane + 64 * k];
#pragma unroll
                for (int jj = 0; jj < 2; ++jj)
#pragma unroll
                    for (int g = 0; g < 4; ++g)
                        acc[jj][g] = dot2acc(w2[jj][g][k], hv, acc[jj][g]);
            }

#pragma unroll
            for (int off = 32; off >= 1; off >>= 1)
#pragma unroll
                for (int jj = 0; jj < 2; ++jj)
#pragma unroll
                    for (int g = 0; g < 4; ++g)
                        acc[jj][g] += __shfl_xor(acc[jj][g], off);

#pragma unroll
            for (int jj = 0; jj < 2; ++jj) {
                float gi = sigmoidf_(acc[jj][0] + bs[jj][0]);
                float gf = sigmoidf_(acc[jj][1] + bs[jj][1]);
                float gg = tanhf_   (acc[jj][2] + bs[jj][2]);
                float go = sigmoidf_(acc[jj][3] + bs[jj][3]);
                cst[jj] = gf * cst[jj] + gi * gg;
                hcur[jj] = go * tanhf_(cst[jj]);
            }
            if (lane == 0) {
                unsigned long long tw = ((unsigned long long)(s + 1)) << 32;
                stg[wave] = tw | pack2(hcur[0], hcur[1]);
                float2 o2 = make_float2(fmaxf(hcur[0], 0.0f), fmaxf(hcur[1], 0.0f));
                *(float2*)(out + (size_t)t * Hn + j0) = o2;   // outputs[t] = relu(h1)
            }
            __syncthreads();                   // barrier B: stg ready; hs2 reads done
            if (wave == 0 && lane < 4) {
                uint4v v = *(const uint4v*)&stg[2 * lane];
                char* dst = (char*)(rowpkt + (size_t)s * ROWP + 512) + blk * 64 + lane * 16;
                store16_coherent(dst, v);      // h1[t] into row s's h1 half
            }
        }
        if (lane == 0) {
#pragma unroll
            for (int jj = 0; jj < 2; ++jj) {
                out[OUTS + Hn + j0 + jj] = hcur[jj];           // hf layer 1
                out[OUTS + 3 * Hn + j0 + jj] = cst[jj];        // cf layer 1
            }
        }
    }
}

extern "C" void kernel_launch(void* const* d_in, const int* in_sizes, int n_in,
                              void* d_out, int out_size, void* d_ws, size_t ws_size,
                              hipStream_t stream) {
    const float* x        = (const float*)d_in[0];
    const int*   ip       = (const int*)d_in[1];
    const int*   port     = (const int*)d_in[2];
    const float* hidden   = (const float*)d_in[3];
    const float* cell     = (const float*)d_in[4];
    const float* ip_emb   = (const float*)d_in[5];
    const float* port_emb = (const float*)d_in[6];
    const float* Wih0     = (const float*)d_in[7];
    const float* Whh0     = (const float*)d_in[8];
    const float* bih0     = (const float*)d_in[9];
    const float* bhh0     = (const float*)d_in[10];
    const float* Wih1     = (const float*)d_in[11];
    const float* Whh1     = (const float*)d_in[12];
    const float* bih1     = (const float*)d_in[13];
    const float* bhh1     = (const float*)d_in[14];
    float* out = (float*)d_out;

    // ws layout: rowpkt ((Bn+1) x 1024 u64 = 33.6 MB) | xin (4096x33 f32).
    // Tags are s+1 in the high 32 bits; 0xAA poison never matches -> no
    // zeroing pass needed.
    unsigned long long* rowpkt = (unsigned long long*)d_ws;
    float* xin = (float*)(rowpkt + (size_t)(Bn + 1) * ROWP);

    prep_kernel<<<dim3((Bn * INW + 255) / 256), dim3(256), 0, stream>>>(
        x, ip, port, ip_emb, port_emb, xin);

    lstm_kernel<<<dim3(96), dim3(TPB), 0, stream>>>(
        xin, hidden, cell, Wih0, Whh0, bih0, bhh0, Wih1, Whh1, bih1, bhh1,
        out, rowpkt);
}